// Round 1
// baseline (239.651 us; speedup 1.0000x reference)
//
#include <hip/hip_runtime.h>

typedef _Float16 f16;
typedef _Float16 half8 __attribute__((ext_vector_type(8)));
typedef float floatx4 __attribute__((ext_vector_type(4)));

#define B_ 64
#define T_ 256
#define C_ 384
#define H_ 6
#define D_ 64
#define NROWS (B_*T_)

typedef __attribute__((address_space(3))) void lds_void_t;
typedef const __attribute__((address_space(1))) void gvoid_t;

__device__ __forceinline__ void g2lds16(const void* g, void* l) {
  __builtin_amdgcn_global_load_lds((gvoid_t*)g, (lds_void_t*)l, 16, 0, 0);
}

// ---------------- weight repack: fp32 -> f16, B^T [N][K] layouts ----------------
__global__ __launch_bounds__(256) void prep_kernel(
    const float* __restrict__ Wq, const float* __restrict__ Wk, const float* __restrict__ Wv,
    const float* __restrict__ bq, const float* __restrict__ bk, const float* __restrict__ bv,
    const float* __restrict__ Wp, const float* __restrict__ W1, const float* __restrict__ W2,
    f16* __restrict__ Wqkv_t, f16* __restrict__ Wp_t, f16* __restrict__ W1_t, f16* __restrict__ W2_t,
    float* __restrict__ bqkv)
{
  int idx = blockIdx.x * 256 + threadIdx.x;
  if (idx < 1152*384) {
    int n = idx / 384, k = idx - n*384;
    const float* W; int nn;
    if (n < 384)      { W = Wq; nn = n; }
    else if (n < 768) { W = Wk; nn = n - 384; }
    else              { W = Wv; nn = n - 768; }
    int h = nn >> 6, d = nn & 63;
    Wqkv_t[idx] = (f16)W[(h*384 + k)*64 + d];
  } else if (idx < 1152*384 + 3*384*384) {
    int j = idx - 1152*384;
    const float* W; f16* O;
    if (j < 147456)        { W = Wp; O = Wp_t; }
    else if (j < 294912)   { W = W1; O = W1_t; j -= 147456; }
    else                   { W = W2; O = W2_t; j -= 294912; }
    int n = j / 384, k = j - n*384;
    O[j] = (f16)W[k*384 + n];
  } else {
    int n = idx - (1152*384 + 3*384*384);
    if (n < 1152) {
      const float* bb; int nn;
      if (n < 384)      { bb = bq; nn = n; }
      else if (n < 768) { bb = bk; nn = n - 384; }
      else              { bb = bv; nn = n - 768; }
      bqkv[n] = bb[nn];
    }
  }
}

// ---------------- layernorm: fp32 in -> f16 out, wave per row ----------------
__global__ __launch_bounds__(256) void ln_kernel(const float* __restrict__ x,
    const float* __restrict__ gamma, const float* __restrict__ beta, f16* __restrict__ out)
{
  int row = blockIdx.x * 4 + (threadIdx.x >> 6);
  int lane = threadIdx.x & 63;
  const float* xr = x + (size_t)row * 384;
  float v[6]; float s = 0.f;
#pragma unroll
  for (int j = 0; j < 6; j++) { v[j] = xr[lane + 64*j]; s += v[j]; }
#pragma unroll
  for (int m = 1; m < 64; m <<= 1) s += __shfl_xor(s, m);
  float mu = s * (1.f/384.f);
  float var = 0.f;
#pragma unroll
  for (int j = 0; j < 6; j++) { float d = v[j]-mu; var += d*d; }
#pragma unroll
  for (int m = 1; m < 64; m <<= 1) var += __shfl_xor(var, m);
  float rs = rsqrtf(var * (1.f/384.f) + 1e-5f);
  f16* orow = out + (size_t)row*384;
#pragma unroll
  for (int j = 0; j < 6; j++) {
    int col = lane + 64*j;
    orow[col] = (f16)((v[j]-mu)*rs*gamma[col] + beta[col]);
  }
}

// ---------------- GEMM: C[M,N] = A[M,384] @ Bt[N,384]^T + bias (m97 structure) ----------------
// MODE 0: f16 out.  MODE 1: f16 relu out.  MODE 2: f32 out + fp32 residual.
template<int MODE>
__global__ __launch_bounds__(256) void gemm_kernel(
    const f16* __restrict__ A, const f16* __restrict__ Bt,
    const float* __restrict__ bias, const float* __restrict__ res,
    void* __restrict__ outp, int ldo)
{
  __shared__ __align__(16) f16 As[128*32];
  __shared__ __align__(16) f16 Bs[128*32];
  const int tid = threadIdx.x;
  const int lane = tid & 63, w = tid >> 6;
  const int wm = w >> 1, wn = w & 1;
  const int q = lane >> 4, c15 = lane & 15;
  const long row0 = (long)blockIdx.x * 128;
  const long col0 = (long)blockIdx.y * 128;
  floatx4 acc[4][4] = {};

  // staging: 512 16B-chunks per tile; thread handles chunks tid and tid+256.
  // physical chunk (row,part) holds logical k-part (part ^ ((row>>1)&3))  [bank swizzle]
  const int c0 = tid,        r0c = c0 >> 2, p0 = c0 & 3, g0 = p0 ^ ((r0c >> 1) & 3);
  const int c1 = 256 + tid,  r1c = c1 >> 2, p1 = c1 & 3, g1 = p1 ^ ((r1c >> 1) & 3);
  const f16* Arow0 = A  + (row0 + r0c)*384 + g0*8;
  const f16* Arow1 = A  + (row0 + r1c)*384 + g1*8;
  const f16* Brow0 = Bt + (col0 + r0c)*384 + g0*8;
  const f16* Brow1 = Bt + (col0 + r1c)*384 + g1*8;
  f16* Adst0 = As + (w*64)*8;
  f16* Adst1 = As + (256 + w*64)*8;
  f16* Bdst0 = Bs + (w*64)*8;
  f16* Bdst1 = Bs + (256 + w*64)*8;

  for (int k0 = 0; k0 < 384; k0 += 32) {
    g2lds16(Arow0 + k0, Adst0);
    g2lds16(Arow1 + k0, Adst1);
    g2lds16(Brow0 + k0, Bdst0);
    g2lds16(Brow1 + k0, Bdst1);
    __syncthreads();
    half8 af[4], bf[4];
#pragma unroll
    for (int mi = 0; mi < 4; mi++) {
      int r = wm*64 + mi*16 + c15;
      int ph = q ^ ((r >> 1) & 3);
      af[mi] = *(const half8*)(As + r*32 + ph*8);
    }
#pragma unroll
    for (int ni = 0; ni < 4; ni++) {
      int r = wn*64 + ni*16 + c15;
      int ph = q ^ ((r >> 1) & 3);
      bf[ni] = *(const half8*)(Bs + r*32 + ph*8);
    }
#pragma unroll
    for (int mi = 0; mi < 4; mi++)
#pragma unroll
      for (int ni = 0; ni < 4; ni++)
        acc[mi][ni] = __builtin_amdgcn_mfma_f32_16x16x32_f16(af[mi], bf[ni], acc[mi][ni], 0, 0, 0);
    __syncthreads();
  }

#pragma unroll
  for (int ni = 0; ni < 4; ni++) {
    long col = col0 + wn*64 + ni*16 + c15;
    float bv = bias[col];
#pragma unroll
    for (int mi = 0; mi < 4; mi++) {
      long rowb = row0 + wm*64 + mi*16 + q*4;
#pragma unroll
      for (int r = 0; r < 4; r++) {
        float vo = acc[mi][ni][r] + bv;
        if (MODE == 1) vo = vo > 0.f ? vo : 0.f;
        long o = (rowb + r) * (long)ldo + col;
        if (MODE == 2) {
          ((float*)outp)[o] = vo + res[o];
        } else {
          ((f16*)outp)[o] = (f16)vo;
        }
      }
    }
  }
}

// ---------------- fused causal attention, one block per (b,h) ----------------
// qkv: [16384][1152] f16, q at col h*64, k at 384+h*64, v at 768+h*64.
// attn_out: [16384][384] f16, head-concat layout.
__global__ __launch_bounds__(256) void attn_kernel(const f16* __restrict__ qkv,
                                                   f16* __restrict__ attn_out)
{
  __shared__ __align__(16) f16 vT[64*256];      // V^T [d][s], xor-swizzled chunks
  __shared__ __align__(16) f16 P[4][16*256];    // per-wave P tile, xor-swizzled
  const int tid = threadIdx.x;
  const int bh = blockIdx.x;
  const int b = bh / 6, h = bh - b*6;
  const f16* qp = qkv + (size_t)b*256*1152 + h*64;
  const f16* kp = qp + 384;
  const f16* vp = qp + 768;

  // load V transposed into LDS (swizzle: phys chunk = (s>>3) ^ (d&15))
#pragma unroll
  for (int i = 0; i < 8; i++) {
    int idx = tid + i*256;
    int s = idx >> 3, part = idx & 7;
    half8 vv = *(const half8*)(vp + (size_t)s*1152 + part*8);
#pragma unroll
    for (int j = 0; j < 8; j++) {
      int d = part*8 + j;
      int ph = (s >> 3) ^ (d & 15);
      vT[d*256 + ph*8 + (s & 7)] = vv[j];
    }
  }
  __syncthreads();

  const int lane = tid & 63, w = tid >> 6;
  const int q = lane >> 4, c15 = lane & 15;
  f16* Pw = &P[w][0];
  const float scale = 0.051031036307982884f;  // 1/sqrt(384)

#pragma unroll 1
  for (int rg = 0; rg < 4; rg++) {
    const int trow0 = w*64 + rg*16;
    const f16* qrow = qp + (size_t)(trow0 + c15)*1152 + q*8;
    half8 aq0 = *(const half8*)(qrow);
    half8 aq1 = *(const half8*)(qrow + 32);
    floatx4 sacc[16];
#pragma unroll
    for (int ni = 0; ni < 16; ni++) {
      const f16* krow = kp + (size_t)(ni*16 + c15)*1152 + q*8;
      half8 b0 = *(const half8*)(krow);
      half8 b1 = *(const half8*)(krow + 32);
      floatx4 a = {0.f, 0.f, 0.f, 0.f};
      a = __builtin_amdgcn_mfma_f32_16x16x32_f16(aq0, b0, a, 0, 0, 0);
      a = __builtin_amdgcn_mfma_f32_16x16x32_f16(aq1, b1, a, 0, 0, 0);
      sacc[ni] = a;
    }
    // mask + scale + row max (C-layout: row = q*4+r, col = ni*16+c15)
    float mx[4] = {-1e30f, -1e30f, -1e30f, -1e30f};
#pragma unroll
    for (int ni = 0; ni < 16; ni++)
#pragma unroll
      for (int r = 0; r < 4; r++) {
        int t = trow0 + q*4 + r;
        int s = ni*16 + c15;
        float vv = sacc[ni][r] * scale;
        vv = (s <= t) ? vv : -1e30f;
        sacc[ni][r] = vv;
        mx[r] = fmaxf(mx[r], vv);
      }
#pragma unroll
    for (int r = 0; r < 4; r++) {
      mx[r] = fmaxf(mx[r], __shfl_xor(mx[r], 1));
      mx[r] = fmaxf(mx[r], __shfl_xor(mx[r], 2));
      mx[r] = fmaxf(mx[r], __shfl_xor(mx[r], 4));
      mx[r] = fmaxf(mx[r], __shfl_xor(mx[r], 8));
    }
    float l[4] = {0.f, 0.f, 0.f, 0.f};
#pragma unroll
    for (int ni = 0; ni < 16; ni++)
#pragma unroll
      for (int r = 0; r < 4; r++) {
        float p = __expf(sacc[ni][r] - mx[r]);
        sacc[ni][r] = p;
        l[r] += p;
      }
#pragma unroll
    for (int r = 0; r < 4; r++) {
      l[r] += __shfl_xor(l[r], 1);
      l[r] += __shfl_xor(l[r], 2);
      l[r] += __shfl_xor(l[r], 4);
      l[r] += __shfl_xor(l[r], 8);
    }
    // write P (f16) to per-wave LDS: C-layout -> memory, swizzled
#pragma unroll
    for (int ni = 0; ni < 16; ni++)
#pragma unroll
      for (int r = 0; r < 4; r++) {
        int row = q*4 + r;
        int col = ni*16 + c15;
        int ph = (col >> 3) ^ row;
        Pw[row*256 + ph*8 + (col & 7)] = (f16)sacc[ni][r];
      }
    // PV: out[16][64] = P[16][256] @ V[256][64]
    floatx4 oacc[4] = {};
#pragma unroll
    for (int kc = 0; kc < 8; kc++) {
      int lc = kc*4 + q;
      half8 ap = *(const half8*)(Pw + c15*256 + (lc ^ c15)*8);
#pragma unroll
      for (int nt = 0; nt < 4; nt++) {
        half8 bv = *(const half8*)(vT + (nt*16 + c15)*256 + (lc ^ c15)*8);
        oacc[nt] = __builtin_amdgcn_mfma_f32_16x16x32_f16(ap, bv, oacc[nt], 0, 0, 0);
      }
    }
#pragma unroll
    for (int nt = 0; nt < 4; nt++)
#pragma unroll
      for (int r = 0; r < 4; r++) {
        int t = trow0 + q*4 + r;
        int d = nt*16 + c15;
        float ov = oacc[nt][r] / l[r];
        attn_out[(size_t)(b*256 + t)*384 + h*64 + d] = (f16)ov;
      }
  }
}

extern "C" void kernel_launch(void* const* d_in, const int* in_sizes, int n_in,
                              void* d_out, int out_size, void* d_ws, size_t ws_size,
                              hipStream_t stream) {
  const float* x   = (const float*)d_in[0];
  const float* Wq  = (const float*)d_in[1];
  const float* bq  = (const float*)d_in[2];
  const float* Wk  = (const float*)d_in[3];
  const float* bk  = (const float*)d_in[4];
  const float* Wv  = (const float*)d_in[5];
  const float* bv  = (const float*)d_in[6];
  const float* Wp  = (const float*)d_in[7];
  const float* bp  = (const float*)d_in[8];
  const float* W1  = (const float*)d_in[9];
  const float* b1  = (const float*)d_in[10];
  const float* W2  = (const float*)d_in[11];
  const float* b2  = (const float*)d_in[12];
  const float* g1  = (const float*)d_in[13];
  const float* be1 = (const float*)d_in[14];
  const float* g2  = (const float*)d_in[15];
  const float* be2 = (const float*)d_in[16];

  char* ws = (char*)d_ws;
  size_t off = 0;
  auto alloc = [&](size_t bytes) -> void* {
    void* p = ws + off;
    off += (bytes + 255) & ~(size_t)255;
    return p;
  };
  f16*   Wqkv_t = (f16*)  alloc(1152*384*sizeof(f16));
  f16*   Wp_t   = (f16*)  alloc(384*384*sizeof(f16));
  f16*   W1_t   = (f16*)  alloc(384*384*sizeof(f16));
  f16*   W2_t   = (f16*)  alloc(384*384*sizeof(f16));
  float* bqkv   = (float*)alloc(1152*sizeof(float));
  f16*   h      = (f16*)  alloc((size_t)NROWS*384*sizeof(f16));
  f16*   qkv    = (f16*)  alloc((size_t)NROWS*1152*sizeof(f16));
  f16*   attnb  = (f16*)  alloc((size_t)NROWS*384*sizeof(f16));
  float* x2     = (float*)alloc((size_t)NROWS*384*sizeof(float));
  f16*   h2     = (f16*)  alloc((size_t)NROWS*384*sizeof(f16));
  f16*   mid    = (f16*)  alloc((size_t)NROWS*384*sizeof(f16));

  // 1. repack weights
  prep_kernel<<<3461, 256, 0, stream>>>(Wq, Wk, Wv, bq, bk, bv, Wp, W1, W2,
                                        Wqkv_t, Wp_t, W1_t, W2_t, bqkv);
  // 2. LN1: x -> h (f16)
  ln_kernel<<<NROWS/4, 256, 0, stream>>>(x, g1, be1, h);
  // 3. QKV: qkv[16384,1152] = h @ Wqkv + bqkv  (f16 out)
  gemm_kernel<0><<<dim3(128, 9), 256, 0, stream>>>(h, Wqkv_t, bqkv, nullptr, qkv, 1152);
  // 4. attention
  attn_kernel<<<B_*H_, 256, 0, stream>>>(qkv, attnb);
  // 5. proj + residual: x2 = x + attn @ Wp + bp  (f32 out)
  gemm_kernel<2><<<dim3(128, 3), 256, 0, stream>>>(attnb, Wp_t, bp, x, x2, 384);
  // 6. LN2: x2 -> h2 (f16)
  ln_kernel<<<NROWS/4, 256, 0, stream>>>(x2, g2, be2, h2);
  // 7. FF1: mid = relu(h2 @ W1 + b1)  (f16 out)
  gemm_kernel<1><<<dim3(128, 3), 256, 0, stream>>>(h2, W1_t, b1, nullptr, mid, 384);
  // 8. FF2: out = x2 + mid @ W2 + b2  (f32 out)
  gemm_kernel<2><<<dim3(128, 3), 256, 0, stream>>>(mid, W2_t, b2, x2, (float*)d_out, 384);
}

// Round 2
// 215.140 us; speedup vs baseline: 1.1139x; 1.1139x over previous
//
#include <hip/hip_runtime.h>

typedef _Float16 f16;
typedef _Float16 half8 __attribute__((ext_vector_type(8)));
typedef _Float16 half4v __attribute__((ext_vector_type(4)));
typedef float floatx4 __attribute__((ext_vector_type(4)));

#define B_ 64
#define T_ 256
#define C_ 384
#define H_ 6
#define D_ 64
#define NROWS (B_*T_)

typedef __attribute__((address_space(3))) void lds_void_t;
typedef const __attribute__((address_space(1))) void gvoid_t;

__device__ __forceinline__ void g2lds16(const void* g, void* l) {
  __builtin_amdgcn_global_load_lds((gvoid_t*)g, (lds_void_t*)l, 16, 0, 0);
}

// ---------------- weight repack: fp32 -> f16, B^T [N][K], coalesced LDS transpose ----------------
// blocks 0..107: Wq/Wk/Wv head-tiles; 108..215: Wp/W1/W2 64x64 tiles; 216: biases.
__global__ __launch_bounds__(256) void prep_kernel(
    const float* __restrict__ Wq, const float* __restrict__ Wk, const float* __restrict__ Wv,
    const float* __restrict__ bq, const float* __restrict__ bk, const float* __restrict__ bv,
    const float* __restrict__ Wp, const float* __restrict__ W1, const float* __restrict__ W2,
    f16* __restrict__ Wqkv_t, f16* __restrict__ Wp_t, f16* __restrict__ W1_t, f16* __restrict__ W2_t,
    float* __restrict__ bqkv)
{
  const int bid = blockIdx.x;
  const int tid = threadIdx.x;
  if (bid == 216) {
    for (int i = tid; i < 1152; i += 256) {
      float v;
      if (i < 384)      v = bq[i];
      else if (i < 768) v = bk[i - 384];
      else              v = bv[i - 768];
      bqkv[i] = v;
    }
    return;
  }
  __shared__ __align__(16) float tile[64*68];
  const float* src; int srcStride; f16* dst;
  if (bid < 108) {
    int mat = bid / 36, rem = bid - mat*36;
    int h = rem / 6, kt = rem - h*6;
    const float* W = (mat == 0) ? Wq : (mat == 1) ? Wk : Wv;
    src = W + (size_t)(h*384 + kt*64)*64;
    srcStride = 64;
    dst = Wqkv_t + (size_t)(mat*384 + h*64)*384 + kt*64;
  } else {
    int b2 = bid - 108;
    int mat = b2 / 36, rem = b2 - mat*36;
    int kt = rem / 6, ct = rem - kt*6;
    const float* W = (mat == 0) ? Wp : (mat == 1) ? W1 : W2;
    src = W + (size_t)(kt*64)*384 + ct*64;
    srcStride = 384;
    f16* O = (mat == 0) ? Wp_t : (mat == 1) ? W1_t : W2_t;
    dst = O + (size_t)(ct*64)*384 + kt*64;
  }
#pragma unroll
  for (int i = 0; i < 4; i++) {
    int idx = i*256 + tid;
    int r = idx >> 4, c4 = idx & 15;
    float4 v = *(const float4*)(src + (size_t)r*srcStride + c4*4);
    *(float4*)(&tile[r*68 + c4*4]) = v;
  }
  __syncthreads();
#pragma unroll
  for (int i = 0; i < 4; i++) {
    int idx = i*256 + tid;
    int d = idx >> 4, k4 = idx & 15;
    half4v o;
#pragma unroll
    for (int j = 0; j < 4; j++) o[j] = (f16)tile[(k4*4 + j)*68 + d];
    *(half4v*)(dst + (size_t)d*384 + k4*4) = o;
  }
}

// ---------------- layernorm: fp32 in -> f16 out, wave per row ----------------
__global__ __launch_bounds__(256) void ln_kernel(const float* __restrict__ x,
    const float* __restrict__ gamma, const float* __restrict__ beta, f16* __restrict__ out)
{
  int row = blockIdx.x * 4 + (threadIdx.x >> 6);
  int lane = threadIdx.x & 63;
  const float* xr = x + (size_t)row * 384;
  float v[6]; float s = 0.f;
#pragma unroll
  for (int j = 0; j < 6; j++) { v[j] = xr[lane + 64*j]; s += v[j]; }
#pragma unroll
  for (int m = 1; m < 64; m <<= 1) s += __shfl_xor(s, m);
  float mu = s * (1.f/384.f);
  float var = 0.f;
#pragma unroll
  for (int j = 0; j < 6; j++) { float d = v[j]-mu; var += d*d; }
#pragma unroll
  for (int m = 1; m < 64; m <<= 1) var += __shfl_xor(var, m);
  float rs = rsqrtf(var * (1.f/384.f) + 1e-5f);
  f16* orow = out + (size_t)row*384;
#pragma unroll
  for (int j = 0; j < 6; j++) {
    int col = lane + 64*j;
    orow[col] = (f16)((v[j]-mu)*rs*gamma[col] + beta[col]);
  }
}

// ---------------- GEMM: C[M,N] = A[M,384] @ Bt[N,384]^T + bias (m97 structure) ----------------
// MODE 0: f16 out.  MODE 1: f16 relu out.  MODE 2: f32 out + fp32 residual.
template<int MODE>
__global__ __launch_bounds__(256) void gemm_kernel(
    const f16* __restrict__ A, const f16* __restrict__ Bt,
    const float* __restrict__ bias, const float* __restrict__ res,
    void* __restrict__ outp, int ldo)
{
  __shared__ __align__(16) f16 As[128*32];
  __shared__ __align__(16) f16 Bs[128*32];
  const int tid = threadIdx.x;
  const int lane = tid & 63, w = tid >> 6;
  const int wm = w >> 1, wn = w & 1;
  const int q = lane >> 4, c15 = lane & 15;
  const long row0 = (long)blockIdx.x * 128;
  const long col0 = (long)blockIdx.y * 128;
  floatx4 acc[4][4] = {};

  const int c0 = tid,        r0c = c0 >> 2, p0 = c0 & 3, g0 = p0 ^ ((r0c >> 1) & 3);
  const int c1 = 256 + tid,  r1c = c1 >> 2, p1 = c1 & 3, g1 = p1 ^ ((r1c >> 1) & 3);
  const f16* Arow0 = A  + (row0 + r0c)*384 + g0*8;
  const f16* Arow1 = A  + (row0 + r1c)*384 + g1*8;
  const f16* Brow0 = Bt + (col0 + r0c)*384 + g0*8;
  const f16* Brow1 = Bt + (col0 + r1c)*384 + g1*8;
  f16* Adst0 = As + (w*64)*8;
  f16* Adst1 = As + (256 + w*64)*8;
  f16* Bdst0 = Bs + (w*64)*8;
  f16* Bdst1 = Bs + (256 + w*64)*8;

  for (int k0 = 0; k0 < 384; k0 += 32) {
    g2lds16(Arow0 + k0, Adst0);
    g2lds16(Arow1 + k0, Adst1);
    g2lds16(Brow0 + k0, Bdst0);
    g2lds16(Brow1 + k0, Bdst1);
    __syncthreads();
    half8 af[4], bf[4];
#pragma unroll
    for (int mi = 0; mi < 4; mi++) {
      int r = wm*64 + mi*16 + c15;
      int ph = q ^ ((r >> 1) & 3);
      af[mi] = *(const half8*)(As + r*32 + ph*8);
    }
#pragma unroll
    for (int ni = 0; ni < 4; ni++) {
      int r = wn*64 + ni*16 + c15;
      int ph = q ^ ((r >> 1) & 3);
      bf[ni] = *(const half8*)(Bs + r*32 + ph*8);
    }
#pragma unroll
    for (int mi = 0; mi < 4; mi++)
#pragma unroll
      for (int ni = 0; ni < 4; ni++)
        acc[mi][ni] = __builtin_amdgcn_mfma_f32_16x16x32_f16(af[mi], bf[ni], acc[mi][ni], 0, 0, 0);
    __syncthreads();
  }

#pragma unroll
  for (int ni = 0; ni < 4; ni++) {
    long col = col0 + wn*64 + ni*16 + c15;
    float bv = bias[col];
#pragma unroll
    for (int mi = 0; mi < 4; mi++) {
      long rowb = row0 + wm*64 + mi*16 + q*4;
#pragma unroll
      for (int r = 0; r < 4; r++) {
        float vo = acc[mi][ni][r] + bv;
        if (MODE == 1) vo = vo > 0.f ? vo : 0.f;
        long o = (rowb + r) * (long)ldo + col;
        if (MODE == 2) {
          ((float*)outp)[o] = vo + res[o];
        } else {
          ((f16*)outp)[o] = (f16)vo;
        }
      }
    }
  }
}

// ---------------- fused causal attention v2 ----------------
// grid: (bh=0..383) x (qt=0..3), blockIdx.x = bh*4 + qt. 256 threads, wave w = 16 Q-rows.
// LDS: 32KB shared region (Ks then vT) + 16KB P (16x128 f16 per wave) = 48KB -> 3 blocks/CU.
__global__ __launch_bounds__(256, 3) void attn_kernel(const f16* __restrict__ qkv,
                                                      f16* __restrict__ attn_out)
{
  __shared__ __align__(16) char kvbuf[32768];
  __shared__ __align__(16) f16 Pbuf[4][16*128];
  f16* Ks = (f16*)kvbuf;           // [s][64], phys chunk p holds logical chunk p^(s&7)
  unsigned int* vTw = (unsigned int*)kvbuf; // word view of V^T [d][128 words]
  f16* vT = (f16*)kvbuf;

  const int tid = threadIdx.x;
  const int bid = blockIdx.x;
  const int bh = bid >> 2, qt = bid & 3;
  const int b = bh / 6, h = bh - b*6;
  const f16* qp = qkv + (size_t)b*256*1152 + h*64;
  const f16* kp = qp + 384;
  const f16* vp = qp + 768;
  const int lane = tid & 63, w = tid >> 6;
  const int q = lane >> 4, c15 = lane & 15;

  // ---- stage K[0..kend) via global_load_lds, swizzled
  {
    const int iters = (qt + 1) * 2;          // kend*8 chunks / 256
    const int pcbase = w*64 + lane;
    for (int i = 0; i < iters; i++) {
      int pc = i*256 + pcbase;
      int rc = pc >> 3, p = pc & 7;
      int c = p ^ (rc & 7);
      g2lds16(kp + (size_t)rc*1152 + c*8, (char*)kvbuf + (size_t)(i*256 + w*64)*16);
    }
  }
  __syncthreads();

  // ---- Q fragments (one-time, direct global)
  const int nmax = qt*4 + w;                 // inclusive diagonal tile index
  const int trow0 = qt*64 + w*16;
  const f16* qrow = qp + (size_t)(trow0 + c15)*1152 + q*8;
  half8 aq0 = *(const half8*)(qrow);
  half8 aq1 = *(const half8*)(qrow + 32);

  // ---- S = QK^T (only tiles 0..nmax)
  floatx4 sacc[16];
#pragma unroll
  for (int ni = 0; ni < 16; ni++) {
    if (ni <= nmax) {
      int s = ni*16 + c15;
      const f16* kr = Ks + s*64;
      int p0 = q ^ (s & 7);
      half8 b0 = *(const half8*)(kr + p0*8);
      half8 b1 = *(const half8*)(kr + (p0 ^ 4)*8);
      floatx4 a = {0.f, 0.f, 0.f, 0.f};
      a = __builtin_amdgcn_mfma_f32_16x16x32_f16(aq0, b0, a, 0, 0, 0);
      a = __builtin_amdgcn_mfma_f32_16x16x32_f16(aq1, b1, a, 0, 0, 0);
      sacc[ni] = a;
    }
  }

  // ---- softmax (C-layout: row=q*4+r, col=ni*16+c15)
  const float scale = 0.051031036307982884f;  // 1/sqrt(384)
  float mx[4] = {-1e30f, -1e30f, -1e30f, -1e30f};
#pragma unroll
  for (int ni = 0; ni < 16; ni++) {
    if (ni < nmax) {
#pragma unroll
      for (int r = 0; r < 4; r++) { float v = sacc[ni][r]*scale; sacc[ni][r] = v; mx[r] = fmaxf(mx[r], v); }
    } else if (ni == nmax) {
#pragma unroll
      for (int r = 0; r < 4; r++) {
        float v = sacc[ni][r]*scale;
        v = (c15 <= q*4 + r) ? v : -1e30f;
        sacc[ni][r] = v; mx[r] = fmaxf(mx[r], v);
      }
    }
  }
#pragma unroll
  for (int r = 0; r < 4; r++) {
    mx[r] = fmaxf(mx[r], __shfl_xor(mx[r], 1));
    mx[r] = fmaxf(mx[r], __shfl_xor(mx[r], 2));
    mx[r] = fmaxf(mx[r], __shfl_xor(mx[r], 4));
    mx[r] = fmaxf(mx[r], __shfl_xor(mx[r], 8));
  }
  float l[4] = {0.f, 0.f, 0.f, 0.f};
#pragma unroll
  for (int ni = 0; ni < 16; ni++) {
    if (ni <= nmax) {
#pragma unroll
      for (int r = 0; r < 4; r++) { float p = __expf(sacc[ni][r] - mx[r]); sacc[ni][r] = p; l[r] += p; }
    }
  }
#pragma unroll
  for (int r = 0; r < 4; r++) {
    l[r] += __shfl_xor(l[r], 1);
    l[r] += __shfl_xor(l[r], 2);
    l[r] += __shfl_xor(l[r], 4);
    l[r] += __shfl_xor(l[r], 8);
  }
  __syncthreads();   // all waves done reading Ks

  // ---- stage V^T into same region: word (d, p*4 + sp&3) = pack(V[2sp][d], V[2sp+1][d])
  // phys chunk p = (sp>>2) ^ (d&15) ^ (d>>3)  -> write banks spread by `part`, reads <=2-way
  {
    const int iters = qt + 1;                // kend*4 items / 256
    for (int i = 0; i < iters; i++) {
      int idx = i*256 + tid;
      int sp = idx >> 3, part = idx & 7;
      const f16* v0 = vp + (size_t)(2*sp)*1152 + part*8;
      half8 va = *(const half8*)(v0);
      half8 vb = *(const half8*)(v0 + 1152);
      int csp = sp >> 2, spw = sp & 3;
#pragma unroll
      for (int j = 0; j < 8; j++) {
        int d = part*8 + j;
        int swz = (d & 15) ^ (d >> 3);
        int p = csp ^ swz;
        union { struct { f16 lo, hi; } s; unsigned int u; } pk;
        pk.s.lo = va[j]; pk.s.hi = vb[j];
        vTw[d*128 + p*4 + spw] = pk.u;
      }
    }
  }
  __syncthreads();

  // ---- PV with chunked per-wave P (16x128 f16), O accumulated in regs
  f16* Pw = &Pbuf[w][0];
  floatx4 oacc[4] = {};
  const int kend_w = (nmax + 1) * 16;
#pragma unroll
  for (int ch = 0; ch < 2; ch++) {
    if (ch*128 < kend_w) {
      // write P tiles of this chunk (f16 scalar, <=2-way banks); zero the partial-32 companion tile
#pragma unroll
      for (int nl = 0; nl < 8; nl++) {
        int ni = ch*8 + nl;
        if (ni <= nmax) {
#pragma unroll
          for (int r = 0; r < 4; r++) {
            int row = q*4 + r;
            int colp = nl*16 + c15;
            int php = (colp >> 3) ^ row;
            Pw[row*128 + php*8 + (colp & 7)] = (f16)sacc[ni][r];
          }
        } else if (ni == nmax + 1) {
#pragma unroll
          for (int r = 0; r < 4; r++) {
            int row = q*4 + r;
            int colp = nl*16 + c15;
            int php = (colp >> 3) ^ row;
            Pw[row*128 + php*8 + (colp & 7)] = (f16)0.f;
          }
        }
      }
#pragma unroll
      for (int kc = 0; kc < 4; kc++) {
        if (ch*128 + kc*32 < kend_w) {
          int pc = (kc*4 + q) ^ c15;
          half8 ap = *(const half8*)(Pw + c15*128 + pc*8);
          int sc = ch*16 + kc*4 + q;     // logical s-chunk
#pragma unroll
          for (int nt = 0; nt < 4; nt++) {
            int d = nt*16 + c15;
            int swz = (d & 15) ^ (d >> 3);
            half8 bv = *(const half8*)(vT + d*256 + ((sc ^ swz))*8);
            oacc[nt] = __builtin_amdgcn_mfma_f32_16x16x32_f16(ap, bv, oacc[nt], 0, 0, 0);
          }
        }
      }
    }
  }

  // ---- store
#pragma unroll
  for (int nt = 0; nt < 4; nt++) {
#pragma unroll
    for (int r = 0; r < 4; r++) {
      int t = trow0 + q*4 + r;
      int d = nt*16 + c15;
      attn_out[(size_t)(b*256 + t)*384 + h*64 + d] = (f16)(oacc[nt][r] / l[r]);
    }
  }
}

extern "C" void kernel_launch(void* const* d_in, const int* in_sizes, int n_in,
                              void* d_out, int out_size, void* d_ws, size_t ws_size,
                              hipStream_t stream) {
  const float* x   = (const float*)d_in[0];
  const float* Wq  = (const float*)d_in[1];
  const float* bq  = (const float*)d_in[2];
  const float* Wk  = (const float*)d_in[3];
  const float* bk  = (const float*)d_in[4];
  const float* Wv  = (const float*)d_in[5];
  const float* bv  = (const float*)d_in[6];
  const float* Wp  = (const float*)d_in[7];
  const float* bp  = (const float*)d_in[8];
  const float* W1  = (const float*)d_in[9];
  const float* b1  = (const float*)d_in[10];
  const float* W2  = (const float*)d_in[11];
  const float* b2  = (const float*)d_in[12];
  const float* g1  = (const float*)d_in[13];
  const float* be1 = (const float*)d_in[14];
  const float* g2  = (const float*)d_in[15];
  const float* be2 = (const float*)d_in[16];

  char* ws = (char*)d_ws;
  size_t off = 0;
  auto alloc = [&](size_t bytes) -> void* {
    void* p = ws + off;
    off += (bytes + 255) & ~(size_t)255;
    return p;
  };
  f16*   Wqkv_t = (f16*)  alloc(1152*384*sizeof(f16));
  f16*   Wp_t   = (f16*)  alloc(384*384*sizeof(f16));
  f16*   W1_t   = (f16*)  alloc(384*384*sizeof(f16));
  f16*   W2_t   = (f16*)  alloc(384*384*sizeof(f16));
  float* bqkv   = (float*)alloc(1152*sizeof(float));
  f16*   h      = (f16*)  alloc((size_t)NROWS*384*sizeof(f16));
  f16*   qkv    = (f16*)  alloc((size_t)NROWS*1152*sizeof(f16));
  f16*   attnb  = (f16*)  alloc((size_t)NROWS*384*sizeof(f16));
  float* x2     = (float*)alloc((size_t)NROWS*384*sizeof(float));
  f16*   h2     = (f16*)  alloc((size_t)NROWS*384*sizeof(f16));
  f16*   mid    = (f16*)  alloc((size_t)NROWS*384*sizeof(f16));

  // 1. repack weights (coalesced LDS transpose)
  prep_kernel<<<217, 256, 0, stream>>>(Wq, Wk, Wv, bq, bk, bv, Wp, W1, W2,
                                       Wqkv_t, Wp_t, W1_t, W2_t, bqkv);
  // 2. LN1: x -> h (f16)
  ln_kernel<<<NROWS/4, 256, 0, stream>>>(x, g1, be1, h);
  // 3. QKV: qkv[16384,1152] = h @ Wqkv + bqkv (f16 out)
  gemm_kernel<0><<<dim3(128, 9), 256, 0, stream>>>(h, Wqkv_t, bqkv, nullptr, qkv, 1152);
  // 4. attention (bh-major grid: 4 qt blocks of one bh adjacent for K/V L2 reuse)
  attn_kernel<<<B_*H_*4, 256, 0, stream>>>(qkv, attnb);
  // 5. proj + residual: x2 = x + attn @ Wp + bp (f32 out)
  gemm_kernel<2><<<dim3(128, 3), 256, 0, stream>>>(attnb, Wp_t, bp, x, x2, 384);
  // 6. LN2: x2 -> h2 (f16)
  ln_kernel<<<NROWS/4, 256, 0, stream>>>(x2, g2, be2, h2);
  // 7. FF1: mid = relu(h2 @ W1 + b1) (f16 out)
  gemm_kernel<1><<<dim3(128, 3), 256, 0, stream>>>(h2, W1_t, b1, nullptr, mid, 384);
  // 8. FF2: out = x2 + mid @ W2 + b2 (f32 out)
  gemm_kernel<2><<<dim3(128, 3), 256, 0, stream>>>(mid, W2_t, b2, x2, (float*)d_out, 384);
}

// Round 3
// 204.180 us; speedup vs baseline: 1.1737x; 1.0537x over previous
//
#include <hip/hip_runtime.h>

typedef _Float16 f16;
typedef _Float16 half8 __attribute__((ext_vector_type(8)));
typedef _Float16 half4v __attribute__((ext_vector_type(4)));
typedef float floatx4 __attribute__((ext_vector_type(4)));

#define B_ 64
#define T_ 256
#define C_ 384
#define H_ 6
#define D_ 64
#define NROWS (B_*T_)

typedef __attribute__((address_space(3))) void lds_void_t;
typedef const __attribute__((address_space(1))) void gvoid_t;

__device__ __forceinline__ void g2lds16(const void* g, void* l) {
  __builtin_amdgcn_global_load_lds((gvoid_t*)g, (lds_void_t*)l, 16, 0, 0);
}

// ---------------- fused prep (weight repack fp32->f16 B^T) + LN1 ----------------
// blocks 0..107: Wq/Wk/Wv head-tiles; 108..215: Wp/W1/W2 64x64 tiles; 216: biases;
// 217..4312: LN1 rows (4 rows/block).
__global__ __launch_bounds__(256) void prep_ln_kernel(
    const float* __restrict__ Wq, const float* __restrict__ Wk, const float* __restrict__ Wv,
    const float* __restrict__ bq, const float* __restrict__ bk, const float* __restrict__ bv,
    const float* __restrict__ Wp, const float* __restrict__ W1, const float* __restrict__ W2,
    f16* __restrict__ Wqkv_t, f16* __restrict__ Wp_t, f16* __restrict__ W1_t, f16* __restrict__ W2_t,
    float* __restrict__ bqkv,
    const float* __restrict__ x, const float* __restrict__ gamma, const float* __restrict__ beta,
    f16* __restrict__ hout)
{
  const int bid = blockIdx.x;
  const int tid = threadIdx.x;
  if (bid >= 217) {
    // ---- LN1: wave per row
    int row = (bid - 217) * 4 + (tid >> 6);
    int lane = tid & 63;
    const float* xr = x + (size_t)row * 384;
    float v[6]; float s = 0.f;
#pragma unroll
    for (int j = 0; j < 6; j++) { v[j] = xr[lane + 64*j]; s += v[j]; }
#pragma unroll
    for (int m = 1; m < 64; m <<= 1) s += __shfl_xor(s, m);
    float mu = s * (1.f/384.f);
    float var = 0.f;
#pragma unroll
    for (int j = 0; j < 6; j++) { float d = v[j]-mu; var += d*d; }
#pragma unroll
    for (int m = 1; m < 64; m <<= 1) var += __shfl_xor(var, m);
    float rs = rsqrtf(var * (1.f/384.f) + 1e-5f);
    f16* orow = hout + (size_t)row*384;
#pragma unroll
    for (int j = 0; j < 6; j++) {
      int col = lane + 64*j;
      orow[col] = (f16)((v[j]-mu)*rs*gamma[col] + beta[col]);
    }
    return;
  }
  if (bid == 216) {
    for (int i = tid; i < 1152; i += 256) {
      float v;
      if (i < 384)      v = bq[i];
      else if (i < 768) v = bk[i - 384];
      else              v = bv[i - 768];
      bqkv[i] = v;
    }
    return;
  }
  __shared__ __align__(16) float tile[64*68];
  const float* src; int srcStride; f16* dst;
  if (bid < 108) {
    int mat = bid / 36, rem = bid - mat*36;
    int h = rem / 6, kt = rem - h*6;
    const float* W = (mat == 0) ? Wq : (mat == 1) ? Wk : Wv;
    src = W + (size_t)(h*384 + kt*64)*64;
    srcStride = 64;
    dst = Wqkv_t + (size_t)(mat*384 + h*64)*384 + kt*64;
  } else {
    int b2 = bid - 108;
    int mat = b2 / 36, rem = b2 - mat*36;
    int kt = rem / 6, ct = rem - kt*6;
    const float* W = (mat == 0) ? Wp : (mat == 1) ? W1 : W2;
    src = W + (size_t)(kt*64)*384 + ct*64;
    srcStride = 384;
    f16* O = (mat == 0) ? Wp_t : (mat == 1) ? W1_t : W2_t;
    dst = O + (size_t)(ct*64)*384 + kt*64;
  }
#pragma unroll
  for (int i = 0; i < 4; i++) {
    int idx = i*256 + tid;
    int r = idx >> 4, c4 = idx & 15;
    float4 v = *(const float4*)(src + (size_t)r*srcStride + c4*4);
    *(float4*)(&tile[r*68 + c4*4]) = v;
  }
  __syncthreads();
#pragma unroll
  for (int i = 0; i < 4; i++) {
    int idx = i*256 + tid;
    int d = idx >> 4, k4 = idx & 15;
    half4v o;
#pragma unroll
    for (int j = 0; j < 4; j++) o[j] = (f16)tile[(k4*4 + j)*68 + d];
    *(half4v*)(dst + (size_t)d*384 + k4*4) = o;
  }
}

// ---------------- layernorm: fp32 in -> f16 out, wave per row ----------------
__global__ __launch_bounds__(256) void ln_kernel(const float* __restrict__ x,
    const float* __restrict__ gamma, const float* __restrict__ beta, f16* __restrict__ out)
{
  int row = blockIdx.x * 4 + (threadIdx.x >> 6);
  int lane = threadIdx.x & 63;
  const float* xr = x + (size_t)row * 384;
  float v[6]; float s = 0.f;
#pragma unroll
  for (int j = 0; j < 6; j++) { v[j] = xr[lane + 64*j]; s += v[j]; }
#pragma unroll
  for (int m = 1; m < 64; m <<= 1) s += __shfl_xor(s, m);
  float mu = s * (1.f/384.f);
  float var = 0.f;
#pragma unroll
  for (int j = 0; j < 6; j++) { float d = v[j]-mu; var += d*d; }
#pragma unroll
  for (int m = 1; m < 64; m <<= 1) var += __shfl_xor(var, m);
  float rs = rsqrtf(var * (1.f/384.f) + 1e-5f);
  f16* orow = out + (size_t)row*384;
#pragma unroll
  for (int j = 0; j < 6; j++) {
    int col = lane + 64*j;
    orow[col] = (f16)((v[j]-mu)*rs*gamma[col] + beta[col]);
  }
}

// ---------------- GEMM: C[M,N] = A[M,384] @ Bt[N,384]^T + bias, BK=64 (2x m97 sub-steps/barrier) ----
// MODE 0: f16 out.  MODE 1: f16 relu out.  MODE 2: f32 out + fp32 residual.
template<int MODE>
__global__ __launch_bounds__(256) void gemm_kernel(
    const f16* __restrict__ A, const f16* __restrict__ Bt,
    const float* __restrict__ bias, const float* __restrict__ res,
    void* __restrict__ outp, int ldo)
{
  __shared__ __align__(16) f16 As[2][128*32];
  __shared__ __align__(16) f16 Bs[2][128*32];
  const int tid = threadIdx.x;
  const int lane = tid & 63, w = tid >> 6;
  const int wm = w >> 1, wn = w & 1;
  const int q = lane >> 4, c15 = lane & 15;
  const long row0 = (long)blockIdx.x * 128;
  const long col0 = (long)blockIdx.y * 128;
  floatx4 acc[4][4] = {};

  const int c0 = tid,        r0c = c0 >> 2, p0 = c0 & 3, g0 = p0 ^ ((r0c >> 1) & 3);
  const int c1 = 256 + tid,  r1c = c1 >> 2, p1 = c1 & 3, g1 = p1 ^ ((r1c >> 1) & 3);
  const f16* Arow0 = A  + (row0 + r0c)*384 + g0*8;
  const f16* Arow1 = A  + (row0 + r1c)*384 + g1*8;
  const f16* Brow0 = Bt + (col0 + r0c)*384 + g0*8;
  const f16* Brow1 = Bt + (col0 + r1c)*384 + g1*8;
  // wave-uniform LDS bases (+ lane*16 implicit)
  const int dof0 = (w*64)*8, dof1 = (256 + w*64)*8;

  for (int k0 = 0; k0 < 384; k0 += 64) {
#pragma unroll
    for (int hf = 0; hf < 2; hf++) {
      int kk = k0 + hf*32;
      g2lds16(Arow0 + kk, &As[hf][dof0]);
      g2lds16(Arow1 + kk, &As[hf][dof1]);
      g2lds16(Brow0 + kk, &Bs[hf][dof0]);
      g2lds16(Brow1 + kk, &Bs[hf][dof1]);
    }
    __syncthreads();
#pragma unroll
    for (int hf = 0; hf < 2; hf++) {
      half8 af[4], bf[4];
#pragma unroll
      for (int mi = 0; mi < 4; mi++) {
        int r = wm*64 + mi*16 + c15;
        int ph = q ^ ((r >> 1) & 3);
        af[mi] = *(const half8*)(&As[hf][r*32 + ph*8]);
      }
#pragma unroll
      for (int ni = 0; ni < 4; ni++) {
        int r = wn*64 + ni*16 + c15;
        int ph = q ^ ((r >> 1) & 3);
        bf[ni] = *(const half8*)(&Bs[hf][r*32 + ph*8]);
      }
#pragma unroll
      for (int mi = 0; mi < 4; mi++)
#pragma unroll
        for (int ni = 0; ni < 4; ni++)
          acc[mi][ni] = __builtin_amdgcn_mfma_f32_16x16x32_f16(af[mi], bf[ni], acc[mi][ni], 0, 0, 0);
    }
    __syncthreads();
  }

#pragma unroll
  for (int ni = 0; ni < 4; ni++) {
    long col = col0 + wn*64 + ni*16 + c15;
    float bv = bias[col];
#pragma unroll
    for (int mi = 0; mi < 4; mi++) {
      long rowb = row0 + wm*64 + mi*16 + q*4;
#pragma unroll
      for (int r = 0; r < 4; r++) {
        float vo = acc[mi][ni][r] + bv;
        if (MODE == 1) vo = vo > 0.f ? vo : 0.f;
        long o = (rowb + r) * (long)ldo + col;
        if (MODE == 2) {
          ((float*)outp)[o] = vo + res[o];
        } else {
          ((f16*)outp)[o] = (f16)vo;
        }
      }
    }
  }
}

// ---------------- fused causal attention (R2 structure, unchanged) ----------------
__global__ __launch_bounds__(256, 3) void attn_kernel(const f16* __restrict__ qkv,
                                                      f16* __restrict__ attn_out)
{
  __shared__ __align__(16) char kvbuf[32768];
  __shared__ __align__(16) f16 Pbuf[4][16*128];
  f16* Ks = (f16*)kvbuf;
  unsigned int* vTw = (unsigned int*)kvbuf;
  f16* vT = (f16*)kvbuf;

  const int tid = threadIdx.x;
  const int bid = blockIdx.x;
  const int bh = bid >> 2, qt = bid & 3;
  const int b = bh / 6, h = bh - b*6;
  const f16* qp = qkv + (size_t)b*256*1152 + h*64;
  const f16* kp = qp + 384;
  const f16* vp = qp + 768;
  const int lane = tid & 63, w = tid >> 6;
  const int q = lane >> 4, c15 = lane & 15;

  {
    const int iters = (qt + 1) * 2;
    const int pcbase = w*64 + lane;
    for (int i = 0; i < iters; i++) {
      int pc = i*256 + pcbase;
      int rc = pc >> 3, p = pc & 7;
      int c = p ^ (rc & 7);
      g2lds16(kp + (size_t)rc*1152 + c*8, (char*)kvbuf + (size_t)(i*256 + w*64)*16);
    }
  }
  __syncthreads();

  const int nmax = qt*4 + w;
  const int trow0 = qt*64 + w*16;
  const f16* qrow = qp + (size_t)(trow0 + c15)*1152 + q*8;
  half8 aq0 = *(const half8*)(qrow);
  half8 aq1 = *(const half8*)(qrow + 32);

  floatx4 sacc[16];
#pragma unroll
  for (int ni = 0; ni < 16; ni++) {
    if (ni <= nmax) {
      int s = ni*16 + c15;
      const f16* kr = Ks + s*64;
      int p0 = q ^ (s & 7);
      half8 b0 = *(const half8*)(kr + p0*8);
      half8 b1 = *(const half8*)(kr + (p0 ^ 4)*8);
      floatx4 a = {0.f, 0.f, 0.f, 0.f};
      a = __builtin_amdgcn_mfma_f32_16x16x32_f16(aq0, b0, a, 0, 0, 0);
      a = __builtin_amdgcn_mfma_f32_16x16x32_f16(aq1, b1, a, 0, 0, 0);
      sacc[ni] = a;
    }
  }

  const float scale = 0.051031036307982884f;
  float mx[4] = {-1e30f, -1e30f, -1e30f, -1e30f};
#pragma unroll
  for (int ni = 0; ni < 16; ni++) {
    if (ni < nmax) {
#pragma unroll
      for (int r = 0; r < 4; r++) { float v = sacc[ni][r]*scale; sacc[ni][r] = v; mx[r] = fmaxf(mx[r], v); }
    } else if (ni == nmax) {
#pragma unroll
      for (int r = 0; r < 4; r++) {
        float v = sacc[ni][r]*scale;
        v = (c15 <= q*4 + r) ? v : -1e30f;
        sacc[ni][r] = v; mx[r] = fmaxf(mx[r], v);
      }
    }
  }
#pragma unroll
  for (int r = 0; r < 4; r++) {
    mx[r] = fmaxf(mx[r], __shfl_xor(mx[r], 1));
    mx[r] = fmaxf(mx[r], __shfl_xor(mx[r], 2));
    mx[r] = fmaxf(mx[r], __shfl_xor(mx[r], 4));
    mx[r] = fmaxf(mx[r], __shfl_xor(mx[r], 8));
  }
  float l[4] = {0.f, 0.f, 0.f, 0.f};
#pragma unroll
  for (int ni = 0; ni < 16; ni++) {
    if (ni <= nmax) {
#pragma unroll
      for (int r = 0; r < 4; r++) { float p = __expf(sacc[ni][r] - mx[r]); sacc[ni][r] = p; l[r] += p; }
    }
  }
#pragma unroll
  for (int r = 0; r < 4; r++) {
    l[r] += __shfl_xor(l[r], 1);
    l[r] += __shfl_xor(l[r], 2);
    l[r] += __shfl_xor(l[r], 4);
    l[r] += __shfl_xor(l[r], 8);
  }
  __syncthreads();

  {
    const int iters = qt + 1;
    for (int i = 0; i < iters; i++) {
      int idx = i*256 + tid;
      int sp = idx >> 3, part = idx & 7;
      const f16* v0 = vp + (size_t)(2*sp)*1152 + part*8;
      half8 va = *(const half8*)(v0);
      half8 vb = *(const half8*)(v0 + 1152);
      int csp = sp >> 2, spw = sp & 3;
#pragma unroll
      for (int j = 0; j < 8; j++) {
        int d = part*8 + j;
        int swz = (d & 15) ^ (d >> 3);
        int p = csp ^ swz;
        union { struct { f16 lo, hi; } s; unsigned int u; } pk;
        pk.s.lo = va[j]; pk.s.hi = vb[j];
        vTw[d*128 + p*4 + spw] = pk.u;
      }
    }
  }
  __syncthreads();

  f16* Pw = &Pbuf[w][0];
  floatx4 oacc[4] = {};
  const int kend_w = (nmax + 1) * 16;
#pragma unroll
  for (int ch = 0; ch < 2; ch++) {
    if (ch*128 < kend_w) {
#pragma unroll
      for (int nl = 0; nl < 8; nl++) {
        int ni = ch*8 + nl;
        if (ni <= nmax) {
#pragma unroll
          for (int r = 0; r < 4; r++) {
            int row = q*4 + r;
            int colp = nl*16 + c15;
            int php = (colp >> 3) ^ row;
            Pw[row*128 + php*8 + (colp & 7)] = (f16)sacc[ni][r];
          }
        } else if (ni == nmax + 1) {
#pragma unroll
          for (int r = 0; r < 4; r++) {
            int row = q*4 + r;
            int colp = nl*16 + c15;
            int php = (colp >> 3) ^ row;
            Pw[row*128 + php*8 + (colp & 7)] = (f16)0.f;
          }
        }
      }
#pragma unroll
      for (int kc = 0; kc < 4; kc++) {
        if (ch*128 + kc*32 < kend_w) {
          int pc = (kc*4 + q) ^ c15;
          half8 ap = *(const half8*)(Pw + c15*128 + pc*8);
          int sc = ch*16 + kc*4 + q;
#pragma unroll
          for (int nt = 0; nt < 4; nt++) {
            int d = nt*16 + c15;
            int swz = (d & 15) ^ (d >> 3);
            half8 bv = *(const half8*)(vT + d*256 + ((sc ^ swz))*8);
            oacc[nt] = __builtin_amdgcn_mfma_f32_16x16x32_f16(ap, bv, oacc[nt], 0, 0, 0);
          }
        }
      }
    }
  }

#pragma unroll
  for (int nt = 0; nt < 4; nt++) {
#pragma unroll
    for (int r = 0; r < 4; r++) {
      int t = trow0 + q*4 + r;
      int d = nt*16 + c15;
      attn_out[(size_t)(b*256 + t)*384 + h*64 + d] = (f16)(oacc[nt][r] / l[r]);
    }
  }
}

extern "C" void kernel_launch(void* const* d_in, const int* in_sizes, int n_in,
                              void* d_out, int out_size, void* d_ws, size_t ws_size,
                              hipStream_t stream) {
  const float* x   = (const float*)d_in[0];
  const float* Wq  = (const float*)d_in[1];
  const float* bq  = (const float*)d_in[2];
  const float* Wk  = (const float*)d_in[3];
  const float* bk  = (const float*)d_in[4];
  const float* Wv  = (const float*)d_in[5];
  const float* bv  = (const float*)d_in[6];
  const float* Wp  = (const float*)d_in[7];
  const float* bp  = (const float*)d_in[8];
  const float* W1  = (const float*)d_in[9];
  const float* b1  = (const float*)d_in[10];
  const float* W2  = (const float*)d_in[11];
  const float* b2  = (const float*)d_in[12];
  const float* g1  = (const float*)d_in[13];
  const float* be1 = (const float*)d_in[14];
  const float* g2  = (const float*)d_in[15];
  const float* be2 = (const float*)d_in[16];

  char* ws = (char*)d_ws;
  size_t off = 0;
  auto alloc = [&](size_t bytes) -> void* {
    void* p = ws + off;
    off += (bytes + 255) & ~(size_t)255;
    return p;
  };
  f16*   Wqkv_t = (f16*)  alloc(1152*384*sizeof(f16));
  f16*   Wp_t   = (f16*)  alloc(384*384*sizeof(f16));
  f16*   W1_t   = (f16*)  alloc(384*384*sizeof(f16));
  f16*   W2_t   = (f16*)  alloc(384*384*sizeof(f16));
  float* bqkv   = (float*)alloc(1152*sizeof(float));
  f16*   h      = (f16*)  alloc((size_t)NROWS*384*sizeof(f16));
  f16*   qkv    = (f16*)  alloc((size_t)NROWS*1152*sizeof(f16));
  f16*   attnb  = (f16*)  alloc((size_t)NROWS*384*sizeof(f16));
  float* x2     = (float*)alloc((size_t)NROWS*384*sizeof(float));
  f16*   h2     = (f16*)  alloc((size_t)NROWS*384*sizeof(f16));
  f16*   mid    = (f16*)  alloc((size_t)NROWS*384*sizeof(f16));

  // 1. fused: weight repack + LN1
  prep_ln_kernel<<<217 + NROWS/4, 256, 0, stream>>>(Wq, Wk, Wv, bq, bk, bv, Wp, W1, W2,
                                                    Wqkv_t, Wp_t, W1_t, W2_t, bqkv,
                                                    x, g1, be1, h);
  // 2. QKV: qkv[16384,1152] = h @ Wqkv + bqkv (f16 out)
  gemm_kernel<0><<<dim3(128, 9), 256, 0, stream>>>(h, Wqkv_t, bqkv, nullptr, qkv, 1152);
  // 3. attention
  attn_kernel<<<B_*H_*4, 256, 0, stream>>>(qkv, attnb);
  // 4. proj + residual: x2 = x + attn @ Wp + bp (f32 out)
  gemm_kernel<2><<<dim3(128, 3), 256, 0, stream>>>(attnb, Wp_t, bp, x, x2, 384);
  // 5. LN2: x2 -> h2 (f16)
  ln_kernel<<<NROWS/4, 256, 0, stream>>>(x2, g2, be2, h2);
  // 6. FF1: mid = relu(h2 @ W1 + b1) (f16 out)
  gemm_kernel<1><<<dim3(128, 3), 256, 0, stream>>>(h2, W1_t, b1, nullptr, mid, 384);
  // 7. FF2: out = x2 + mid @ W2 + b2 (f32 out)
  gemm_kernel<2><<<dim3(128, 3), 256, 0, stream>>>(mid, W2_t, b2, x2, (float*)d_out, 384);
}